// Round 12
// baseline (212.455 us; speedup 1.0000x reference)
//
#include <hip/hip_runtime.h>
#include <hip/hip_cooperative_groups.h>

// out[128,16384] = [A|B](128x8384) @ [x; x2](8384x16384), bf16 MFMA.
// Round 12 = r9's gemm (best measured: 66us) fused with prep into ONE
// cooperative kernel. Evidence: >=2 graph nodes costs ~58us of inter-node
// overhead (r1: 1 node, gap 0; r9/r10/r11: 2 nodes, gap ~58; r5/r7: 4, ~63).
// Phase 0: 256 blocks build wt (analytic K-perm, r10-verified) + zero out,
//          stage xt/ppc; __threadfence (device-scope release, cross-XCD G16);
//          grid.sync(); Phase 1: r9 gemm body (512thr, 128x128 tile, splitK x2,
//          af reg double-buffer, barrier-free K-loop).
// K-perm: identity k'<128 | NICE [128,7936) jb-major, C(jb)=jb(4jb-3) |
// RAGGED [7936,8384) i-major leftovers.
// DO NOT add __launch_bounds__ min-waves: (256,8) clamped VGPR -> spills (r6).

namespace cg = cooperative_groups;

constexpr int N_     = 128;
constexpr int S_     = 8256;
constexpr int BATCH_ = 16384;
constexpr int NKT    = 131;          // 8384/64
constexpr int LD     = 136;          // xt row stride (ushorts); rows 272B = 17x16B
constexpr int NWT    = NKT * 8192;   // 1,073,152 wt elements

typedef __attribute__((ext_vector_type(8))) short short8;
typedef __attribute__((ext_vector_type(4))) float f32x4;
typedef __attribute__((ext_vector_type(2))) float f32x2;

__device__ __forceinline__ float bf2f(ushort h) {
    unsigned u = (unsigned)h << 16;
    float f;
    __builtin_memcpy(&f, &u, 4);
    return f;
}
__device__ __forceinline__ ushort f2bf(float f) {   // RNE
    unsigned u;
    __builtin_memcpy(&u, &f, 4);
    u = (u + 0x7FFFu + ((u >> 16) & 1u)) >> 16;
    return (ushort)u;
}
__device__ __forceinline__ uint fbits(float f) {
    uint u; __builtin_memcpy(&u, &f, 4); return u;
}

// NICE octet o in [0,976) -> i | (j0<<8).  C(jb) = jb*(4jb-3); i = o - C(jb).
__device__ __forceinline__ uint nice_octet(int o) {
    float f = sqrtf(9.0f + 16.0f * (float)o);
    int jb = (int)((3.0f + f) * 0.125f);
    while (jb * (4 * jb - 3) > o) --jb;
    while ((jb + 1) * (4 * jb + 1) <= o) ++jb;
    const int i = o - jb * (4 * jb - 3);
    return (uint)i | ((uint)(jb << 3) << 8);
}

// RAGGED index c in [0,448) -> i | (j<<8).
__device__ __forceinline__ uint rag_pair(int c) {
    const int blk = c / 28, rem = c - blk * 28;
    int r, tb;
    if      (rem >= 27) { r = 7; tb = 27; }
    else if (rem >= 25) { r = 6; tb = 25; }
    else if (rem >= 22) { r = 5; tb = 22; }
    else if (rem >= 18) { r = 4; tb = 18; }
    else if (rem >= 13) { r = 3; tb = 13; }
    else if (rem >= 7)  { r = 2; tb = 7;  }
    else                { r = 1; tb = 0;  }
    const int i = blk * 8 + r;
    const int j = i + (rem - tb);
    return (uint)i | ((uint)j << 8);
}

__device__ __forceinline__ float w_value(const float* __restrict__ A,
                                         const float* __restrict__ B,
                                         int m, int k) {
    if (k < 128) return A[m * 128 + k];
    uint p;
    if (k < 7936) {
        p = nice_octet((k - 128) >> 3);
        p += (uint)(k & 7) << 8;            // j = j0 + e
    } else {
        p = rag_pair(k - 7936);
    }
    const int i = (int)(p & 0xFFu), j = (int)(p >> 8);
    const int s = i * (257 - i) / 2 + (j - i);
    return B[(size_t)m * S_ + s];
}

// A-frags for step kt: 8 lane-linear b128 loads (coalesced wt layout:
// elem e = kt*8192 + (((kk*2+wm)*4+mt)*64+lane)*8 + el).
__device__ __forceinline__ void load_af(short8 af[8], const ushort* __restrict__ wt,
                                        int kt, int wm, int lane) {
    const ushort* ab = wt + ((size_t)kt << 13) + (wm << 11) + (lane << 3);
    #pragma unroll
    for (int kk = 0; kk < 2; ++kk)
        #pragma unroll
        for (int mt = 0; mt < 4; ++mt)
            af[kk * 4 + mt] = *(const short8*)(ab + (kk << 12) + (mt << 9));
}

// NICE-step: gen B-frags from compact pair word + MFMA.
__device__ __forceinline__ void step_nice(f32x4 acc[4][2], const short8 af[8],
                                          uint prc, const ushort* __restrict__ xr0,
                                          const ushort* __restrict__ xr1) {
    const uint i0a = prc & 0xFFu, j0a = (prc >> 8) & 0xFFu;
    const uint i0b = (prc >> 16) & 0xFFu, j0b = prc >> 24;
    const ushort xia0 = xr0[i0a], xia1 = xr1[i0a];
    const ushort xib0 = xr0[i0b], xib1 = xr1[i0b];
    uint wa0[4], wa1[4], wb0[4], wb1[4];
    __builtin_memcpy(wa0, xr0 + j0a, 16);
    __builtin_memcpy(wa1, xr1 + j0a, 16);
    __builtin_memcpy(wb0, xr0 + j0b, 16);
    __builtin_memcpy(wb1, xr1 + j0b, 16);

    short8 bfr[2][2];
    #pragma unroll
    for (int v = 0; v < 4; ++v) {
        const uint*  wsx = (v == 0) ? wa0 : (v == 1) ? wa1 : (v == 2) ? wb0 : wb1;
        const ushort xis = (v == 0) ? xia0 : (v == 1) ? xia1 : (v == 2) ? xib0 : xib1;
        const float xi = bf2f(xis);
        const f32x2 xi2 = {xi, xi};
        uint ow[4];
        #pragma unroll
        for (int p = 0; p < 4; ++p) {
            const uint lo = wsx[p] << 16;
            const uint hi = wsx[p] & 0xFFFF0000u;
            f32x2 a;
            { float fl, fh;
              __builtin_memcpy(&fl, &lo, 4);
              __builtin_memcpy(&fh, &hi, 4);
              a.x = fl; a.y = fh; }
            const f32x2 o = a * xi2;                      // v_pk_mul_f32
            ow[p] = __builtin_amdgcn_perm(fbits(o.y), fbits(o.x),
                                          0x07060302u);   // hi16|hi16 trunc pack
        }
        __builtin_memcpy(&bfr[v >> 1][v & 1], ow, 16);
    }
    #pragma unroll
    for (int kk = 0; kk < 2; ++kk)
        #pragma unroll
        for (int mt = 0; mt < 4; ++mt)
            #pragma unroll
            for (int nt = 0; nt < 2; ++nt)
                acc[mt][nt] = __builtin_amdgcn_mfma_f32_16x16x32_bf16(
                    af[kk * 4 + mt], bfr[kk][nt], acc[mt][nt], 0, 0, 0);
}

// ---------- single cooperative kernel: prep + grid.sync + GEMM ----------
__global__ __launch_bounds__(512) void fused_all(
    const float* __restrict__ x,
    const float* __restrict__ A,
    const float* __restrict__ B,
    ushort* __restrict__ wt,
    float* __restrict__ out)
{
    __shared__ ushort xt[128 * LD];    // 34.8 KB: xt[n*LD + r] = bf16 x[r][b0+n]
    __shared__ uint   ppc[NKT * 4];    // 2.1 KB

    const int t    = threadIdx.x;
    const int b0   = blockIdx.x * 128;
    const int sp   = blockIdx.y;
    const int kt0  = sp ? 66 : 0;
    const int kt1  = sp ? NKT : 66;
    const int lane = t & 63;
    const int w    = t >> 6;
    const int wm   = w >> 2, wn = w & 3;
    const int l16  = lane & 15, quad = lane >> 4;

    // ======== phase 0a: distributed zero-out + wt build ========
    const int bid  = blockIdx.y * 128 + blockIdx.x;   // 0..255
    const int gtid = bid * 512 + t;                   // 0..131071
    {
        const float4 z4 = make_float4(0.f, 0.f, 0.f, 0.f);
        #pragma unroll
        for (int q = 0; q < 4; ++q)                   // 524288 float4 exactly
            ((float4*)out)[q * 131072 + gtid] = z4;
        for (int e = gtid; e < NWT; e += 131072) {    // 9 strided iters (last partial)
            const int kt = e >> 13;
            const int r  = e & 8191;
            const int kk = r >> 12;
            const int wmm = (r >> 11) & 1;
            const int mt = (r >> 9) & 3;
            const int ln = (r >> 3) & 63;
            const int el = r & 7;
            const int m  = wmm * 64 + mt * 16 + (ln & 15);
            const int k  = kt * 64 + kk * 32 + (ln >> 4) * 8 + el;
            wt[e] = f2bf(w_value(A, B, m, k));
        }
    }

    // ======== phase 0b: stage xt + ppc (local, overlaps other blocks' prep) ====
    {
        const int n = t & 127, g = t >> 7;
        #pragma unroll
        for (int c = 0; c < 4; ++c) {
            const int rb = g * 32 + c * 8;
            uint ow[4];
            #pragma unroll
            for (int p = 0; p < 4; ++p) {
                const ushort u0 = f2bf(x[(size_t)(rb + 2 * p) * BATCH_ + b0 + n]);
                const ushort u1 = f2bf(x[(size_t)(rb + 2 * p + 1) * BATCH_ + b0 + n]);
                ow[p] = (uint)u0 | ((uint)u1 << 16);
            }
            __builtin_memcpy(&xt[n * LD + rb], ow, 16);
        }
    }
    for (int idx = t; idx < NKT * 4; idx += 512) {
        const int kt = idx >> 2, q = idx & 3;
        uint v = 0;
        const int k0 = kt * 64 + q * 8;
        if (k0 >= 128 && k0 + 32 < 7936) {
            const uint a = nice_octet((k0 - 128) >> 3);
            const uint b = nice_octet((k0 + 32 - 128) >> 3);
            v = a | (b << 16);
        }
        ppc[idx] = v;
    }

    // ======== device-scope release of wt + grid-wide barrier ========
    __threadfence();                 // agent-scope: cross-XCD visibility (G16)
    cg::this_grid().sync();          // also block-level barrier for xt/ppc

    // ======== phase 1: GEMM (r9 body) ========
    f32x4 acc[4][2];
    #pragma unroll
    for (int mt = 0; mt < 4; ++mt)
        #pragma unroll
        for (int nt = 0; nt < 2; ++nt)
            acc[mt][nt] = (f32x4){0.f, 0.f, 0.f, 0.f};

    const ushort* xr0 = xt + (wn * 32 + l16) * LD;
    const ushort* xr1 = xr0 + 16 * LD;

    // ---- identity steps (kt = 0,1; sp==0 only) ----
    if (sp == 0) {
        for (int kt = 0; kt < 2; ++kt) {
            short8 af[8];
            load_af(af, wt, kt, wm, lane);
            short8 bfr[2][2];
            #pragma unroll
            for (int kk = 0; kk < 2; ++kk) {
                const int off = kt * 64 + kk * 32 + quad * 8;
                bfr[kk][0] = *(const short8*)(xr0 + off);
                bfr[kk][1] = *(const short8*)(xr1 + off);
            }
            #pragma unroll
            for (int kk = 0; kk < 2; ++kk)
                #pragma unroll
                for (int mt = 0; mt < 4; ++mt)
                    #pragma unroll
                    for (int nt = 0; nt < 2; ++nt)
                        acc[mt][nt] = __builtin_amdgcn_mfma_f32_16x16x32_bf16(
                            af[kk * 4 + mt], bfr[kk][nt], acc[mt][nt], 0, 0, 0);
        }
    }

    // ---- NICE steps, software-pipelined af double-buffer ----
    {
        const int s_ni = (kt0 > 2) ? kt0 : 2;
        const int e_ni = (kt1 < 124) ? kt1 : 124;
        int kt = s_ni;
        if (kt < e_ni) {
            short8 afA[8], afB[8];
            load_af(afA, wt, kt, wm, lane);
            uint prc = ppc[kt * 4 + quad];
            while (true) {
                {   // consume afA, prefetch afB
                    const int ktn = (kt + 1 < e_ni) ? kt + 1 : kt;
                    load_af(afB, wt, ktn, wm, lane);
                    const uint prn = ppc[ktn * 4 + quad];
                    step_nice(acc, afA, prc, xr0, xr1);
                    prc = prn; ++kt;
                }
                if (kt >= e_ni) break;
                {   // consume afB, prefetch afA
                    const int ktn = (kt + 1 < e_ni) ? kt + 1 : kt;
                    load_af(afA, wt, ktn, wm, lane);
                    const uint prn = ppc[ktn * 4 + quad];
                    step_nice(acc, afB, prc, xr0, xr1);
                    prc = prn; ++kt;
                }
                if (kt >= e_ni) break;
            }
        }
    }

    // ---- ragged steps (kt = 124..130; sp==1 only) ----
    if (sp == 1) {
        for (int kt = 124; kt < NKT; ++kt) {
            short8 af[8];
            load_af(af, wt, kt, wm, lane);
            short8 bfr[2][2];
            #pragma unroll
            for (int kk = 0; kk < 2; ++kk) {
                const int cb = kt * 64 + kk * 32 + quad * 8 - 7936;
                uint prs[8];
                #pragma unroll
                for (int e = 0; e < 8; ++e) prs[e] = rag_pair(cb + e);
                #pragma unroll
                for (int nt = 0; nt < 2; ++nt) {
                    const ushort* xr = nt ? xr1 : xr0;
                    float prods[8];
                    #pragma unroll
                    for (int e = 0; e < 8; ++e)
                        prods[e] = bf2f(xr[prs[e] & 0xFFu]) * bf2f(xr[prs[e] >> 8]);
                    uint ow[4];
                    #pragma unroll
                    for (int p = 0; p < 4; ++p)
                        ow[p] = __builtin_amdgcn_perm(fbits(prods[2 * p + 1]),
                                                      fbits(prods[2 * p]),
                                                      0x07060302u);
                    __builtin_memcpy(&bfr[kk][nt], ow, 16);
                }
            }
            #pragma unroll
            for (int kk = 0; kk < 2; ++kk)
                #pragma unroll
                for (int mt = 0; mt < 4; ++mt)
                    #pragma unroll
                    for (int nt = 0; nt < 2; ++nt)
                        acc[mt][nt] = __builtin_amdgcn_mfma_f32_16x16x32_bf16(
                            af[kk * 4 + mt], bfr[kk][nt], acc[mt][nt], 0, 0, 0);
        }
    }

    // ---- epilogue: atomic accumulate (C/D: col=lane&15, row=quad*4+reg) ----
    #pragma unroll
    for (int mt = 0; mt < 4; ++mt) {
        #pragma unroll
        for (int nt = 0; nt < 2; ++nt) {
            const int mbase = wm * 64 + mt * 16 + quad * 4;
            const size_t col = (size_t)b0 + wn * 32 + nt * 16 + l16;
            #pragma unroll
            for (int r = 0; r < 4; ++r)
                unsafeAtomicAdd(&out[(size_t)(mbase + r) * BATCH_ + col],
                                acc[mt][nt][r]);
        }
    }
}

extern "C" void kernel_launch(void* const* d_in, const int* in_sizes, int n_in,
                              void* d_out, int out_size, void* d_ws, size_t ws_size,
                              hipStream_t stream) {
    const float* x = (const float*)d_in[0];   // [128, 16384]
    const float* A = (const float*)d_in[1];   // [128, 128]
    const float* B = (const float*)d_in[2];   // [128, 8256]
    float* out = (float*)d_out;               // [128, 16384]
    ushort* wt = (ushort*)d_ws;

    void* args[] = {(void*)&x, (void*)&A, (void*)&B, (void*)&wt, (void*)&out};
    hipLaunchCooperativeKernel((const void*)fused_all,
                               dim3(BATCH_ / 128, 2), dim3(512),
                               args, 0, stream);
}

// Round 13
// 133.276 us; speedup vs baseline: 1.5941x; 1.5941x over previous
//
#include <hip/hip_runtime.h>

// out[128,16384] = [A|B](128x8384) @ [x; x2](8384x16384), bf16 MFMA.
// Round 13 = r9 core, restructured gen:
//   - K-perm NICE region now QUAD-CHUNKED jb-major: octet o = quad*244 +
//     (kt-2)*2 + kk. Each quad walks its 244 octets sequentially, so the
//     per-row j-window (b128) lives in PERSISTENT REGISTERS and reloads only
//     at jb-run boundaries (runs 8jb+1 long; ~3-9 reloads/split). Per-step
//     LDS drops from 8 ops to 8 ds_read_u16 (xi only). State (i, jb)
//     advances incrementally -> no pair table at all.
//   - wave tile 64x64 (256-thr blocks, 128x128 tile, 4x4 frags, split-K x4,
//     512 blocks = 2 blocks/CU): af L2 traffic halves (~490 MB), 32 MFMA/step.
//   - 2 dispatches: prep (zero + wt build, analytic perm) + gemm.
// NOTE (r12): ~60us/replay is HARNESS-FIXED (0xAA re-poison of 268MB ws+out);
// single-kernel/cooperative fusion does NOT remove it and grid.sync regressed.
// DO NOT add __launch_bounds__ min-waves: clamped VGPR -> spills (r6).
// K-perm: identity k'<128 | NICE [128,7936) quad-chunked jb-major,
// C(jb)=jb(4jb-3) | RAGGED [7936,8384) i-major leftovers (rag_pair).

constexpr int N_     = 128;
constexpr int S_     = 8256;
constexpr int BATCH_ = 16384;
constexpr int NKT    = 131;          // 8384/64
constexpr int LD     = 136;          // xt row stride (ushorts); rows 272B = 17x16B
constexpr int NWT    = NKT * 8192;   // wt elements

typedef __attribute__((ext_vector_type(8))) short short8;
typedef __attribute__((ext_vector_type(4))) float f32x4;
typedef __attribute__((ext_vector_type(2))) float f32x2;

__device__ __forceinline__ float bf2f(ushort h) {
    unsigned u = (unsigned)h << 16;
    float f;
    __builtin_memcpy(&f, &u, 4);
    return f;
}
__device__ __forceinline__ ushort f2bf(float f) {   // RNE
    unsigned u;
    __builtin_memcpy(&u, &f, 4);
    u = (u + 0x7FFFu + ((u >> 16) & 1u)) >> 16;
    return (ushort)u;
}
__device__ __forceinline__ uint fbits(float f) {
    uint u; __builtin_memcpy(&u, &f, 4); return u;
}

// NICE octet o in [0,976) -> i | (j0<<8).  C(jb) = jb*(4jb-3); i = o - C(jb).
__device__ __forceinline__ uint nice_octet(int o) {
    float f = sqrtf(9.0f + 16.0f * (float)o);
    int jb = (int)((3.0f + f) * 0.125f);
    while (jb * (4 * jb - 3) > o) --jb;
    while ((jb + 1) * (4 * jb + 1) <= o) ++jb;
    const int i = o - jb * (4 * jb - 3);
    return (uint)i | ((uint)(jb << 3) << 8);
}

// RAGGED index c in [0,448) -> i | (j<<8).
__device__ __forceinline__ uint rag_pair(int c) {
    const int blk = c / 28, rem = c - blk * 28;
    int r, tb;
    if      (rem >= 27) { r = 7; tb = 27; }
    else if (rem >= 25) { r = 6; tb = 25; }
    else if (rem >= 22) { r = 5; tb = 22; }
    else if (rem >= 18) { r = 4; tb = 18; }
    else if (rem >= 13) { r = 3; tb = 13; }
    else if (rem >= 7)  { r = 2; tb = 7;  }
    else                { r = 1; tb = 0;  }
    const int i = blk * 8 + r;
    const int j = i + (rem - tb);
    return (uint)i | ((uint)j << 8);
}

__device__ __forceinline__ float w_value(const float* __restrict__ A,
                                         const float* __restrict__ B,
                                         int m, int k) {
    if (k < 128) return A[m * 128 + k];
    int i, j;
    if (k < 7936) {
        const int kt = k >> 6, kk = (k >> 5) & 1, quad = (k >> 3) & 3, el = k & 7;
        const int o = quad * 244 + (kt - 2) * 2 + kk;   // quad-chunked jb-major
        const uint pi = nice_octet(o);
        i = (int)(pi & 0xFFu);
        j = (int)(pi >> 8) + el;
    } else {
        const uint p = rag_pair(k - 7936);
        i = (int)(p & 0xFFu);
        j = (int)(p >> 8);
    }
    const int s = i * (257 - i) / 2 + (j - i);
    return B[(size_t)m * S_ + s];
}

// ---------- phase 1: prep = zero out (blocks 0..2047) + build wt ----------
// wt coalesced layout: elem e = kt*8192 + (((kk*2+wm)*4+mt)*64+lane)*8 + el holds
// W[m = wm*64+mt*16+(lane&15)][ perm(kt*64 + kk*32 + (lane>>4)*8 + el) ]
__global__ void prep(const float* __restrict__ A, const float* __restrict__ B,
                     ushort* __restrict__ wt, float* __restrict__ out) {
    const int b = blockIdx.x;
    if (b < 2048) {
        ((float4*)out)[b * 256 + threadIdx.x] = make_float4(0.f, 0.f, 0.f, 0.f);
        return;
    }
    const int e  = (b - 2048) * 256 + threadIdx.x;   // 4192*256 = 131*8192 exactly
    const int kt = e >> 13;
    const int r  = e & 8191;
    const int kk = r >> 12;
    const int wmm = (r >> 11) & 1;
    const int mt = (r >> 9) & 3;
    const int lane = (r >> 3) & 63;
    const int el = r & 7;
    const int m  = wmm * 64 + mt * 16 + (lane & 15);
    const int k  = kt * 64 + kk * 32 + (lane >> 4) * 8 + el;
    wt[e] = f2bf(w_value(A, B, m, k));
}

// A-frags for step kt: 8 lane-linear b128 loads (coalesced layout).
__device__ __forceinline__ void load_af(short8 af[8], const ushort* __restrict__ wt,
                                        int kt, int wm, int lane) {
    const ushort* ab = wt + ((size_t)kt << 13) + (wm << 11) + (lane << 3);
    #pragma unroll
    for (int kk = 0; kk < 2; ++kk)
        #pragma unroll
        for (int mt = 0; mt < 4; ++mt)
            af[kk * 4 + mt] = *(const short8*)(ab + (kk << 12) + (mt << 9));
}

// reload persistent j-windows (4 rows x b128) for current jb
__device__ __forceinline__ void reload_wnd(uint wnd[4][4],
                                           const ushort* const xrs[4], int jb) {
    #pragma unroll
    for (int r = 0; r < 4; ++r)
        __builtin_memcpy(wnd[r], xrs[r] + jb * 8, 16);
}

// gen 4 B-frags (one per nt row) for one octet at state (i, windows)
__device__ __forceinline__ void gen_octet(short8 bfr[4], const uint wnd[4][4],
                                          const ushort* const xrs[4], int i) {
    uint xiu[4];
    #pragma unroll
    for (int r = 0; r < 4; ++r) xiu[r] = xrs[r][i];   // 4 ds_read_u16
    #pragma unroll
    for (int r = 0; r < 4; ++r) {
        const uint xb = xiu[r] << 16;
        float xf;
        __builtin_memcpy(&xf, &xb, 4);
        const f32x2 xi2 = {xf, xf};
        uint ow[4];
        #pragma unroll
        for (int p = 0; p < 4; ++p) {
            const uint lo = wnd[r][p] << 16;
            const uint hi = wnd[r][p] & 0xFFFF0000u;
            f32x2 a;
            { float fl, fh;
              __builtin_memcpy(&fl, &lo, 4);
              __builtin_memcpy(&fh, &hi, 4);
              a.x = fl; a.y = fh; }
            const f32x2 o = a * xi2;                      // v_pk_mul_f32
            ow[p] = __builtin_amdgcn_perm(fbits(o.y), fbits(o.x),
                                          0x07060302u);   // hi16|hi16 trunc pack
        }
        __builtin_memcpy(&bfr[r], ow, 16);
    }
}

// one NICE step: 2 octets (kk=0,1), incremental (i, jb, windows) state
__device__ __forceinline__ void step_nice(f32x4 acc[4][4], const short8 af[8],
                                          int& i, int& jb, uint wnd[4][4],
                                          const ushort* const xrs[4]) {
    short8 b0_[4];
    gen_octet(b0_, wnd, xrs, i);
    #pragma unroll
    for (int mt = 0; mt < 4; ++mt)
        #pragma unroll
        for (int nt = 0; nt < 4; ++nt)
            acc[mt][nt] = __builtin_amdgcn_mfma_f32_16x16x32_bf16(
                af[mt], b0_[nt], acc[mt][nt], 0, 0, 0);
    ++i;
    if (i > 8 * jb) { ++jb; i = 0; reload_wnd(wnd, xrs, jb); }

    short8 b1_[4];
    gen_octet(b1_, wnd, xrs, i);
    #pragma unroll
    for (int mt = 0; mt < 4; ++mt)
        #pragma unroll
        for (int nt = 0; nt < 4; ++nt)
            acc[mt][nt] = __builtin_amdgcn_mfma_f32_16x16x32_bf16(
                af[4 + mt], b1_[nt], acc[mt][nt], 0, 0, 0);
    ++i;
    if (i > 8 * jb) { ++jb; i = 0; reload_wnd(wnd, xrs, jb); }
}

// ---------- phase 2: GEMM, 128x128 tile, 4 waves, wave tile 64x64, splitK x4 ----------
__global__ __launch_bounds__(256) void gemm_mfma(
    const float*  __restrict__ x,
    const ushort* __restrict__ wt,
    float* __restrict__ out)
{
    __shared__ ushort xt[128 * LD];    // 34.8 KB: xt[n*LD + r] = bf16 x[r][b0+n]

    const int t    = threadIdx.x;
    const int b0   = blockIdx.x * 128;
    const int sp   = blockIdx.y;                   // 0..3
    const int KTS[5] = {2, 33, 64, 94, 124};       // NICE split boundaries
    const int lane = t & 63;
    const int w    = t >> 6;
    const int wm   = w >> 1, wn = w & 1;
    const int l16  = lane & 15, quad = lane >> 4;

    // ---- stage xt: coalesced global reads, RNE, b128 LDS writes ----
    {
        const int n = t & 127, g = t >> 7;         // 2 threads per column
        #pragma unroll
        for (int c = 0; c < 8; ++c) {
            const int rb = g * 64 + c * 8;
            uint ow[4];
            #pragma unroll
            for (int p = 0; p < 4; ++p) {
                const ushort u0 = f2bf(x[(size_t)(rb + 2 * p) * BATCH_ + b0 + n]);
                const ushort u1 = f2bf(x[(size_t)(rb + 2 * p + 1) * BATCH_ + b0 + n]);
                ow[p] = (uint)u0 | ((uint)u1 << 16);
            }
            __builtin_memcpy(&xt[n * LD + rb], ow, 16);
        }
    }
    __syncthreads();

    f32x4 acc[4][4];
    #pragma unroll
    for (int mt = 0; mt < 4; ++mt)
        #pragma unroll
        for (int nt = 0; nt < 4; ++nt)
            acc[mt][nt] = (f32x4){0.f, 0.f, 0.f, 0.f};

    const ushort* xrs[4];
    #pragma unroll
    for (int r = 0; r < 4; ++r)
        xrs[r] = xt + (wn * 64 + r * 16 + l16) * LD;

    // ---- identity steps (kt = 0,1; sp==0 only) ----
    if (sp == 0) {
        for (int kt = 0; kt < 2; ++kt) {
            short8 af[8];
            load_af(af, wt, kt, wm, lane);
            #pragma unroll
            for (int kk = 0; kk < 2; ++kk) {
                const int off = kt * 64 + kk * 32 + quad * 8;
                short8 bfr[4];
                #pragma unroll
                for (int nt = 0; nt < 4; ++nt)
                    bfr[nt] = *(const short8*)(xrs[nt] + off);
                #pragma unroll
                for (int mt = 0; mt < 4; ++mt)
                    #pragma unroll
                    for (int nt = 0; nt < 4; ++nt)
                        acc[mt][nt] = __builtin_amdgcn_mfma_f32_16x16x32_bf16(
                            af[kk * 4 + mt], bfr[nt], acc[mt][nt], 0, 0, 0);
            }
        }
    }

    // ---- NICE steps: incremental (i, jb, window) state + af double-buffer ----
    {
        const int s_ni = KTS[sp], e_ni = KTS[sp + 1];
        int i, jb;
        uint wnd[4][4];
        {
            const int o0 = quad * 244 + (s_ni - 2) * 2;
            const uint pi = nice_octet(o0);
            i  = (int)(pi & 0xFFu);
            jb = (int)(pi >> 11);                 // (pi>>8)/8
            reload_wnd(wnd, xrs, jb);
        }
        int kt = s_ni;
        short8 afA[8], afB[8];
        load_af(afA, wt, kt, wm, lane);
        while (true) {
            {   // consume afA, prefetch afB
                const int ktn = (kt + 1 < e_ni) ? kt + 1 : kt;
                load_af(afB, wt, ktn, wm, lane);
                step_nice(acc, afA, i, jb, wnd, xrs);
                ++kt;
            }
            if (kt >= e_ni) break;
            {   // consume afB, prefetch afA
                const int ktn = (kt + 1 < e_ni) ? kt + 1 : kt;
                load_af(afA, wt, ktn, wm, lane);
                step_nice(acc, afB, i, jb, wnd, xrs);
                ++kt;
            }
            if (kt >= e_ni) break;
        }
    }

    // ---- ragged steps (kt = 124..130; sp==3 only) ----
    if (sp == 3) {
        for (int kt = 124; kt < NKT; ++kt) {
            short8 af[8];
            load_af(af, wt, kt, wm, lane);
            #pragma unroll
            for (int kk = 0; kk < 2; ++kk) {
                const int cb = kt * 64 + kk * 32 + quad * 8 - 7936;
                uint prs[8];
                #pragma unroll
                for (int e = 0; e < 8; ++e) prs[e] = rag_pair(cb + e);
                short8 bfr[4];
                #pragma unroll
                for (int nt = 0; nt < 4; ++nt) {
                    const ushort* xr = xrs[nt];
                    float prods[8];
                    #pragma unroll
                    for (int e = 0; e < 8; ++e)
                        prods[e] = bf2f(xr[prs[e] & 0xFFu]) * bf2f(xr[prs[e] >> 8]);
                    uint ow[4];
                    #pragma unroll
                    for (int p = 0; p < 4; ++p)
                        ow[p] = __builtin_amdgcn_perm(fbits(prods[2 * p + 1]),
                                                      fbits(prods[2 * p]),
                                                      0x07060302u);
                    __builtin_memcpy(&bfr[nt], ow, 16);
                }
                #pragma unroll
                for (int mt = 0; mt < 4; ++mt)
                    #pragma unroll
                    for (int nt = 0; nt < 4; ++nt)
                        acc[mt][nt] = __builtin_amdgcn_mfma_f32_16x16x32_bf16(
                            af[kk * 4 + mt], bfr[nt], acc[mt][nt], 0, 0, 0);
            }
        }
    }

    // ---- epilogue: atomic accumulate (C/D: col=lane&15, row=quad*4+reg) ----
    #pragma unroll
    for (int mt = 0; mt < 4; ++mt) {
        #pragma unroll
        for (int nt = 0; nt < 4; ++nt) {
            const int mbase = wm * 64 + mt * 16 + quad * 4;
            const size_t col = (size_t)b0 + wn * 64 + nt * 16 + l16;
            #pragma unroll
            for (int r = 0; r < 4; ++r)
                unsafeAtomicAdd(&out[(size_t)(mbase + r) * BATCH_ + col],
                                acc[mt][nt][r]);
        }
    }
}

extern "C" void kernel_launch(void* const* d_in, const int* in_sizes, int n_in,
                              void* d_out, int out_size, void* d_ws, size_t ws_size,
                              hipStream_t stream) {
    const float* x = (const float*)d_in[0];   // [128, 16384]
    const float* A = (const float*)d_in[1];   // [128, 128]
    const float* B = (const float*)d_in[2];   // [128, 8256]
    float* out = (float*)d_out;               // [128, 16384]
    ushort* wt = (ushort*)d_ws;

    prep<<<2048 + 4192, 256, 0, stream>>>(A, B, wt, out);
    gemm_mfma<<<dim3(BATCH_ / 128, 4), 256, 0, stream>>>(x, wt, out);
}

// Round 14
// 126.888 us; speedup vs baseline: 1.6743x; 1.0503x over previous
//
#include <hip/hip_runtime.h>

// out[128,16384] = [A|B](128x8384) @ [x; x2](8384x16384), bf16 MFMA.
// Round 14 = r9 (best: gemm 66us; 512thr, 128x128 tile, splitK x2, af reg
// double-buffer) + GEN RAW-WINDOW PIPELINING: the 8 gen LDS reads for step
// kt+1 are issued before step kt's VALU+MFMA, carried in GenRaw A/B register
// buffers. Removes the ~170cyc lgkm wait from the per-step serial chain
// (cycle model: 1215 -> ~800 cyc/step-pair).
// Prep = r10's analytic 2-dispatch version (zero+wt build; no pair table).
// K-perm: identity k'<128 | NICE [128,7936) jb-major octets (o=(k-128)>>3,
// C(jb)=jb(4jb-3)) | RAGGED [7936,8384) i-major leftovers.
// Lessons pinned: no __launch_bounds__ min-waves (r6: VGPR clamp -> spills);
// ~60us/replay is harness-fixed re-poison cost (r12), not inter-node gaps;
// 256-block 1-blk/CU grid beats all wider-split variants (r8-r13).

constexpr int N_     = 128;
constexpr int S_     = 8256;
constexpr int BATCH_ = 16384;
constexpr int NKT    = 131;          // 8384/64
constexpr int LD     = 136;          // xt row stride (ushorts); rows 272B = 17x16B

typedef __attribute__((ext_vector_type(8))) short short8;
typedef __attribute__((ext_vector_type(4))) float f32x4;
typedef __attribute__((ext_vector_type(2))) float f32x2;

__device__ __forceinline__ float bf2f(ushort h) {
    unsigned u = (unsigned)h << 16;
    float f;
    __builtin_memcpy(&f, &u, 4);
    return f;
}
__device__ __forceinline__ ushort f2bf(float f) {   // RNE
    unsigned u;
    __builtin_memcpy(&u, &f, 4);
    u = (u + 0x7FFFu + ((u >> 16) & 1u)) >> 16;
    return (ushort)u;
}
__device__ __forceinline__ uint fbits(float f) {
    uint u; __builtin_memcpy(&u, &f, 4); return u;
}

// NICE octet o in [0,976) -> i | (j0<<8).  C(jb) = jb*(4jb-3); i = o - C(jb).
__device__ __forceinline__ uint nice_octet(int o) {
    float f = sqrtf(9.0f + 16.0f * (float)o);
    int jb = (int)((3.0f + f) * 0.125f);
    while (jb * (4 * jb - 3) > o) --jb;
    while ((jb + 1) * (4 * jb + 1) <= o) ++jb;
    const int i = o - jb * (4 * jb - 3);
    return (uint)i | ((uint)(jb << 3) << 8);
}

// RAGGED index c in [0,448) -> i | (j<<8).
__device__ __forceinline__ uint rag_pair(int c) {
    const int blk = c / 28, rem = c - blk * 28;
    int r, tb;
    if      (rem >= 27) { r = 7; tb = 27; }
    else if (rem >= 25) { r = 6; tb = 25; }
    else if (rem >= 22) { r = 5; tb = 22; }
    else if (rem >= 18) { r = 4; tb = 18; }
    else if (rem >= 13) { r = 3; tb = 13; }
    else if (rem >= 7)  { r = 2; tb = 7;  }
    else                { r = 1; tb = 0;  }
    const int i = blk * 8 + r;
    const int j = i + (rem - tb);
    return (uint)i | ((uint)j << 8);
}

__device__ __forceinline__ float w_value(const float* __restrict__ A,
                                         const float* __restrict__ B,
                                         int m, int k) {
    if (k < 128) return A[m * 128 + k];
    uint p;
    if (k < 7936) {
        p = nice_octet((k - 128) >> 3);
        p += (uint)(k & 7) << 8;            // j = j0 + e
    } else {
        p = rag_pair(k - 7936);
    }
    const int i = (int)(p & 0xFFu), j = (int)(p >> 8);
    const int s = i * (257 - i) / 2 + (j - i);
    return B[(size_t)m * S_ + s];
}

// ---------- phase 1: prep = zero out (blocks 0..2047) + build wt ----------
// wt coalesced layout: elem e = kt*8192 + (((kk*2+wm)*4+mt)*64+lane)*8 + el holds
// W[m = wm*64+mt*16+(lane&15)][ perm(kt*64 + kk*32 + (lane>>4)*8 + el) ]
__global__ void prep(const float* __restrict__ A, const float* __restrict__ B,
                     ushort* __restrict__ wt, float* __restrict__ out) {
    const int b = blockIdx.x;
    if (b < 2048) {
        ((float4*)out)[b * 256 + threadIdx.x] = make_float4(0.f, 0.f, 0.f, 0.f);
        return;
    }
    const int e  = (b - 2048) * 256 + threadIdx.x;   // 4192*256 = 131*8192 exactly
    const int kt = e >> 13;
    const int r  = e & 8191;
    const int kk = r >> 12;
    const int wmm = (r >> 11) & 1;
    const int mt = (r >> 9) & 3;
    const int lane = (r >> 3) & 63;
    const int el = r & 7;
    const int m  = wmm * 64 + mt * 16 + (lane & 15);
    const int k  = kt * 64 + kk * 32 + (lane >> 4) * 8 + el;
    wt[e] = f2bf(w_value(A, B, m, k));
}

// A-frags for step kt: 8 lane-linear b128 loads (coalesced layout).
__device__ __forceinline__ void load_af(short8 af[8], const ushort* __restrict__ wt,
                                        int kt, int wm, int lane) {
    const ushort* ab = wt + ((size_t)kt << 13) + (wm << 11) + (lane << 3);
    #pragma unroll
    for (int kk = 0; kk < 2; ++kk)
        #pragma unroll
        for (int mt = 0; mt < 4; ++mt)
            af[kk * 4 + mt] = *(const short8*)(ab + (kk << 12) + (mt << 9));
}

// Raw gen inputs for one step, held in registers across the pipeline stage.
struct GenRaw {
    uint w[4][4];    // 4 j-windows (b128 each): [a,row0],[a,row1],[b,row0],[b,row1]
    uint xi[4];      // 4 xi scalars (zero-extended u16)
};

// Issue the 8 LDS reads for step whose compact pair word is prc.
__device__ __forceinline__ void gen_read(GenRaw& g, uint prc,
                                         const ushort* __restrict__ xr0,
                                         const ushort* __restrict__ xr1) {
    const uint i0a = prc & 0xFFu, j0a = (prc >> 8) & 0xFFu;
    const uint i0b = (prc >> 16) & 0xFFu, j0b = prc >> 24;
    g.xi[0] = xr0[i0a];
    g.xi[1] = xr1[i0a];
    g.xi[2] = xr0[i0b];
    g.xi[3] = xr1[i0b];
    __builtin_memcpy(g.w[0], xr0 + j0a, 16);
    __builtin_memcpy(g.w[1], xr1 + j0a, 16);
    __builtin_memcpy(g.w[2], xr0 + j0b, 16);
    __builtin_memcpy(g.w[3], xr1 + j0b, 16);
}

// VALU gen (packed mul + trunc pack) + 16 MFMA, consuming a landed GenRaw.
__device__ __forceinline__ void gen_mfma(f32x4 acc[4][2], const short8 af[8],
                                         const GenRaw& g) {
    short8 bfr[2][2];
    #pragma unroll
    for (int v = 0; v < 4; ++v) {
        const uint xb = g.xi[v] << 16;
        float xf;
        __builtin_memcpy(&xf, &xb, 4);
        const f32x2 xi2 = {xf, xf};
        uint ow[4];
        #pragma unroll
        for (int p = 0; p < 4; ++p) {
            const uint lo = g.w[v][p] << 16;
            const uint hi = g.w[v][p] & 0xFFFF0000u;
            f32x2 a;
            { float fl, fh;
              __builtin_memcpy(&fl, &lo, 4);
              __builtin_memcpy(&fh, &hi, 4);
              a.x = fl; a.y = fh; }
            const f32x2 o = a * xi2;                      // v_pk_mul_f32
            ow[p] = __builtin_amdgcn_perm(fbits(o.y), fbits(o.x),
                                          0x07060302u);   // hi16|hi16 trunc pack
        }
        __builtin_memcpy(&bfr[v >> 1][v & 1], ow, 16);
    }
    #pragma unroll
    for (int kk = 0; kk < 2; ++kk)
        #pragma unroll
        for (int mt = 0; mt < 4; ++mt)
            #pragma unroll
            for (int nt = 0; nt < 2; ++nt)
                acc[mt][nt] = __builtin_amdgcn_mfma_f32_16x16x32_bf16(
                    af[kk * 4 + mt], bfr[kk][nt], acc[mt][nt], 0, 0, 0);
}

// ---------- phase 2: fused MFMA GEMM, 128x128 tile, split-K x2 ----------
__global__ __launch_bounds__(512) void gemm_mfma(
    const float*  __restrict__ x,
    const ushort* __restrict__ wt,
    float* __restrict__ out)
{
    __shared__ ushort xt[128 * LD];    // 34.8 KB: xt[n*LD + r] = bf16 x[r][b0+n]
    __shared__ uint   ppc[NKT * 4];    // 2.1 KB

    const int t    = threadIdx.x;
    const int b0   = blockIdx.x * 128;
    const int sp   = blockIdx.y;
    const int kt0  = sp ? 66 : 0;
    const int kt1  = sp ? NKT : 66;
    const int lane = t & 63;
    const int w    = t >> 6;
    const int wm   = w >> 2, wn = w & 3;
    const int l16  = lane & 15, quad = lane >> 4;

    // ---- stage xt: coalesced global reads, RNE, b128 LDS writes ----
    {
        const int n = t & 127, g = t >> 7;
        #pragma unroll
        for (int c = 0; c < 4; ++c) {
            const int rb = g * 32 + c * 8;
            uint ow[4];
            #pragma unroll
            for (int p = 0; p < 4; ++p) {
                const ushort u0 = f2bf(x[(size_t)(rb + 2 * p) * BATCH_ + b0 + n]);
                const ushort u1 = f2bf(x[(size_t)(rb + 2 * p + 1) * BATCH_ + b0 + n]);
                ow[p] = (uint)u0 | ((uint)u1 << 16);
            }
            __builtin_memcpy(&xt[n * LD + rb], ow, 16);
        }
    }
    // ---- build ppc analytically (NICE kts only) ----
    for (int idx = t; idx < NKT * 4; idx += 512) {
        const int kt = idx >> 2, q = idx & 3;
        uint v = 0;
        const int k0 = kt * 64 + q * 8;
        if (k0 >= 128 && k0 + 32 < 7936) {
            const uint a = nice_octet((k0 - 128) >> 3);
            const uint b = nice_octet((k0 + 32 - 128) >> 3);
            v = a | (b << 16);
        }
        ppc[idx] = v;
    }
    __syncthreads();

    f32x4 acc[4][2];
    #pragma unroll
    for (int mt = 0; mt < 4; ++mt)
        #pragma unroll
        for (int nt = 0; nt < 2; ++nt)
            acc[mt][nt] = (f32x4){0.f, 0.f, 0.f, 0.f};

    const ushort* xr0 = xt + (wn * 32 + l16) * LD;
    const ushort* xr1 = xr0 + 16 * LD;

    // ================= identity steps (kt = 0,1; sp==0 only) =================
    if (sp == 0) {
        for (int kt = 0; kt < 2; ++kt) {
            short8 af[8];
            load_af(af, wt, kt, wm, lane);
            short8 bfr[2][2];
            #pragma unroll
            for (int kk = 0; kk < 2; ++kk) {
                const int off = kt * 64 + kk * 32 + quad * 8;
                bfr[kk][0] = *(const short8*)(xr0 + off);
                bfr[kk][1] = *(const short8*)(xr1 + off);
            }
            #pragma unroll
            for (int kk = 0; kk < 2; ++kk)
                #pragma unroll
                for (int mt = 0; mt < 4; ++mt)
                    #pragma unroll
                    for (int nt = 0; nt < 2; ++nt)
                        acc[mt][nt] = __builtin_amdgcn_mfma_f32_16x16x32_bf16(
                            af[kk * 4 + mt], bfr[kk][nt], acc[mt][nt], 0, 0, 0);
        }
    }

    // ===== NICE steps: af double-buffer + GenRaw (LDS) double-buffer =====
    {
        const int s_ni = (kt0 > 2) ? kt0 : 2;
        const int e_ni = (kt1 < 124) ? kt1 : 124;
        int kt = s_ni;
        if (kt < e_ni) {
            short8 afA[8], afB[8];
            GenRaw rawA, rawB;
            load_af(afA, wt, kt, wm, lane);
            gen_read(rawA, ppc[kt * 4 + quad], xr0, xr1);
            while (true) {
                {   // consume afA/rawA (step kt); prefetch B for kt+1
                    const int ktn = (kt + 1 < e_ni) ? kt + 1 : kt;
                    load_af(afB, wt, ktn, wm, lane);
                    gen_read(rawB, ppc[ktn * 4 + quad], xr0, xr1);
                    gen_mfma(acc, afA, rawA);
                    ++kt;
                }
                if (kt >= e_ni) break;
                {   // consume afB/rawB; prefetch A
                    const int ktn = (kt + 1 < e_ni) ? kt + 1 : kt;
                    load_af(afA, wt, ktn, wm, lane);
                    gen_read(rawA, ppc[ktn * 4 + quad], xr0, xr1);
                    gen_mfma(acc, afB, rawB);
                    ++kt;
                }
                if (kt >= e_ni) break;
            }
        }
    }

    // ================= ragged steps (kt = 124..130; sp==1 only) =================
    if (sp == 1) {
        for (int kt = 124; kt < NKT; ++kt) {
            short8 af[8];
            load_af(af, wt, kt, wm, lane);
            short8 bfr[2][2];
            #pragma unroll
            for (int kk = 0; kk < 2; ++kk) {
                const int cb = kt * 64 + kk * 32 + quad * 8 - 7936;
                uint prs[8];
                #pragma unroll
                for (int e = 0; e < 8; ++e) prs[e] = rag_pair(cb + e);
                #pragma unroll
                for (int nt = 0; nt < 2; ++nt) {
                    const ushort* xr = nt ? xr1 : xr0;
                    float prods[8];
                    #pragma unroll
                    for (int e = 0; e < 8; ++e)
                        prods[e] = bf2f(xr[prs[e] & 0xFFu]) * bf2f(xr[prs[e] >> 8]);
                    uint ow[4];
                    #pragma unroll
                    for (int p = 0; p < 4; ++p)
                        ow[p] = __builtin_amdgcn_perm(fbits(prods[2 * p + 1]),
                                                      fbits(prods[2 * p]),
                                                      0x07060302u);
                    __builtin_memcpy(&bfr[kk][nt], ow, 16);
                }
            }
            #pragma unroll
            for (int kk = 0; kk < 2; ++kk)
                #pragma unroll
                for (int mt = 0; mt < 4; ++mt)
                    #pragma unroll
                    for (int nt = 0; nt < 2; ++nt)
                        acc[mt][nt] = __builtin_amdgcn_mfma_f32_16x16x32_bf16(
                            af[kk * 4 + mt], bfr[kk][nt], acc[mt][nt], 0, 0, 0);
        }
    }

    // ---- epilogue: atomic accumulate (C/D: col=lane&15, row=quad*4+reg) ----
    #pragma unroll
    for (int mt = 0; mt < 4; ++mt) {
        #pragma unroll
        for (int nt = 0; nt < 2; ++nt) {
            const int mbase = wm * 64 + mt * 16 + quad * 4;
            const size_t col = (size_t)b0 + wn * 32 + nt * 16 + l16;
            #pragma unroll
            for (int r = 0; r < 4; ++r)
                unsafeAtomicAdd(&out[(size_t)(mbase + r) * BATCH_ + col],
                                acc[mt][nt][r]);
        }
    }
}

extern "C" void kernel_launch(void* const* d_in, const int* in_sizes, int n_in,
                              void* d_out, int out_size, void* d_ws, size_t ws_size,
                              hipStream_t stream) {
    const float* x = (const float*)d_in[0];   // [128, 16384]
    const float* A = (const float*)d_in[1];   // [128, 128]
    const float* B = (const float*)d_in[2];   // [128, 8256]
    float* out = (float*)d_out;               // [128, 16384]
    ushort* wt = (ushort*)d_ws;

    prep<<<2048 + 4192, 256, 0, stream>>>(A, B, wt, out);
    gemm_mfma<<<dim3(BATCH_ / 128, 2), 512, 0, stream>>>(x, wt, out);
}